// Round 6
// baseline (101.322 us; speedup 1.0000x reference)
//
#include <hip/hip_runtime.h>
#include <stdint.h>

typedef unsigned short u16;
typedef unsigned int   u32;

#define NB 4
#define N1 8192
#define N2 2048
#define C1 128
#define C2 256
#define KK1 384          // C2 + C1
#define FF 256
#define TM 64
#define TILES_PER_B (N1 / TM)   // 128

typedef short short8 __attribute__((ext_vector_type(8)));
typedef float floatx4 __attribute__((ext_vector_type(4)));

union ABFrag { u32 u[4]; short8 v; };

__device__ __forceinline__ float b2f(u16 u) {
    union { u32 i; float f; } c; c.i = ((u32)u) << 16; return c.f;
}
__device__ __forceinline__ u16 f2b(float f) {
    u32 x = __float_as_uint(f);
    return (u16)((x + 0x7FFFu + ((x >> 16) & 1u)) >> 16);
}
__device__ __forceinline__ u32 pack2(float a, float b) {
    return (u32)f2b(a) | ((u32)f2b(b) << 16);
}

// ---- fused: 3nn + interp + concat + mlp(2x); f32 in, f32 out ----
__global__ __launch_bounds__(256) void fp_fused_kernel(
    const float* __restrict__ xyz1, const float* __restrict__ xyz2,
    const float* __restrict__ p1,   const float* __restrict__ p2,
    const float* __restrict__ w1,   const float* __restrict__ w2,
    float* __restrict__ out)
{
    __shared__ int   s_idx[TM][3];
    __shared__ float s_wt[TM][3];
    __shared__ __align__(16) char s_buf[TM * 392 * 2];   // 50176 B, multi-phase

    const int tid = threadIdx.x;
    const int b   = blockIdx.x / TILES_PER_B;
    const int t0  = (blockIdx.x % TILES_PER_B) * TM;

    // ---------- phase 1: 3-NN ----------
    float4* xp = (float4*)s_buf;                              // [N2] (x,y,z,|x|^2)
    float*  pd = (float*)(s_buf + N2 * 16);                   // [4][TM][3]
    int*    pi = (int*)  (s_buf + N2 * 16 + 4 * TM * 3 * 4);  // [4][TM][3]

    for (int j = tid; j < N2; j += 256) {
        const float* q = xyz2 + ((size_t)b * N2 + j) * 3;
        float x = q[0], y = q[1], z = q[2];
        float s2 = __fadd_rn(__fadd_rn(__fmul_rn(x,x), __fmul_rn(y,y)), __fmul_rn(z,z));
        xp[j] = make_float4(x, y, z, s2);
    }
    __syncthreads();

    {
        const int r = tid & 63, ch = tid >> 6;
        const float* q = xyz1 + ((size_t)b * N1 + t0 + r) * 3;
        float qx = q[0], qy = q[1], qz = q[2];
        float s1 = __fadd_rn(__fadd_rn(__fmul_rn(qx,qx), __fmul_rn(qy,qy)), __fmul_rn(qz,qz));
        float bd0 = 3e38f, bd1 = 3e38f, bd2 = 3e38f;
        int   bi0 = 0, bi1 = 0, bi2 = 0;
        const int j0 = ch * (N2 / 4);
        for (int j = j0; j < j0 + N2 / 4; ++j) {
            float4 p = xp[j];
            // match np expanded form, plain mul/add (no fma contraction)
            float t  = __fadd_rn(__fadd_rn(__fmul_rn(qx,p.x), __fmul_rn(qy,p.y)), __fmul_rn(qz,p.z));
            float d  = __fsub_rn(__fadd_rn(s1, p.w), __fmul_rn(2.0f, t));
            if (d < bd2) {
                if (d < bd1) {
                    bd2 = bd1; bi2 = bi1;
                    if (d < bd0) { bd1 = bd0; bi1 = bi0; bd0 = d; bi0 = j; }
                    else         { bd1 = d;  bi1 = j; }
                } else { bd2 = d; bi2 = j; }
            }
        }
        const int o = (ch * TM + r) * 3;
        pd[o+0] = bd0; pd[o+1] = bd1; pd[o+2] = bd2;
        pi[o+0] = bi0; pi[o+1] = bi1; pi[o+2] = bi2;
    }
    __syncthreads();

    if (tid < TM) {
        float d0 = 3e38f, d1 = 3e38f, d2 = 3e38f;
        int   i0 = 0, i1 = 0, i2 = 0;
        for (int c = 0; c < 4; ++c) {
            const int o = (c * TM + tid) * 3;
            #pragma unroll
            for (int k = 0; k < 3; ++k) {
                float d = pd[o + k]; int ix = pi[o + k];
                if (d < d2) {
                    if (d < d1) {
                        d2 = d1; i2 = i1;
                        if (d < d0) { d1 = d0; i1 = i0; d0 = d; i0 = ix; }
                        else        { d1 = d;  i1 = ix; }
                    } else { d2 = d; i2 = ix; }
                }
            }
        }
        d0 = fmaxf(d0, 1e-10f); d1 = fmaxf(d1, 1e-10f); d2 = fmaxf(d2, 1e-10f);
        float v0 = 1.0f / d0, v1 = 1.0f / d1, v2 = 1.0f / d2;
        float s  = 1.0f / (v0 + v1 + v2);
        s_wt[tid][0] = v0 * s; s_wt[tid][1] = v1 * s; s_wt[tid][2] = v2 * s;
        s_idx[tid][0] = i0; s_idx[tid][1] = i1; s_idx[tid][2] = i2;
    }
    __syncthreads();

    // ---------- phase 2: A tile = [interp | points1], bf16 [TM][392] ----------
    u16* A = (u16*)s_buf;
    {
        const float* pb = p2 + (size_t)b * N2 * C2;
        for (int rr = 0; rr < TM; ++rr) {
            float w0 = s_wt[rr][0], w1v = s_wt[rr][1], w2v = s_wt[rr][2];
            int   i0 = s_idx[rr][0], i1 = s_idx[rr][1], i2 = s_idx[rr][2];
            float acc = w0  * pb[i0 * C2 + tid]
                      + w1v * pb[i1 * C2 + tid]
                      + w2v * pb[i2 * C2 + tid];
            A[rr * 392 + tid] = f2b(acc);
        }
        const int c = tid & 127, r2 = tid >> 7;
        for (int rr = r2; rr < TM; rr += 2)
            A[rr * 392 + 256 + c] = f2b(p1[((size_t)b * N1 + t0 + rr) * C1 + c]);
    }
    __syncthreads();

    // ---------- phase 2.5: empirical C/D map probe (2 MFMAs) ----------
    const int lane = tid & 63;
    const int wv   = tid >> 6;          // wave -> column quarter
    const int lr   = lane & 15;
    const int lg   = lane >> 4;         // k-group 0..3
    const int lk   = lg << 2;           // 0,4,8,12
    const int wvb  = wv * 64;

    floatx4 D1, D2;
    {
        u16 rbf = f2b((float)lr);        // 0..15, exact in bf16
        u16 c32 = f2b(1.0f / 32.0f);     // 2^-5, exact
        ABFrag pa, pc;
        u32 ra = (u32)rbf | ((u32)rbf << 16);
        u32 rc = (u32)c32 | ((u32)c32 << 16);
        pa.u[0] = pa.u[1] = pa.u[2] = pa.u[3] = ra;
        pc.u[0] = pc.u[1] = pc.u[2] = pc.u[3] = rc;
        floatx4 z = {0.f, 0.f, 0.f, 0.f};
        D1 = __builtin_amdgcn_mfma_f32_16x16x32_bf16(pa.v, pc.v, z, 0, 0, 0); // D1[g] = row of (lane,g)
        D2 = __builtin_amdgcn_mfma_f32_16x16x32_bf16(pc.v, pa.v, z, 0, 0, 0); // D2[g] = col of (lane,g)
    }

    // ---------- phase 3: GEMM1 (K=384), W1 fragments from global f32 ----------
    floatx4 acc[4][4];
    #pragma unroll
    for (int i = 0; i < 4; ++i)
        #pragma unroll
        for (int j = 0; j < 4; ++j) acc[i][j] = floatx4{0.f, 0.f, 0.f, 0.f};

    for (int kk = 0; kk < KK1 / 32; ++kk) {
        const int kb = kk * 32 + lk;
        ABFrag a[4];
        #pragma unroll
        for (int rt = 0; rt < 4; ++rt) {
            const u32* ap = (const u32*)(A + (rt * 16 + lr) * 392 + kb);
            a[rt].u[0] = ap[0]; a[rt].u[1] = ap[1];
            a[rt].u[2] = ap[8]; a[rt].u[3] = ap[9];
        }
        #pragma unroll
        for (int ctl = 0; ctl < 4; ++ctl) {
            const float* wk = w1 + (size_t)kb * FF + (wvb + ctl * 16 + lr);
            ABFrag bf;
            bf.u[0] = pack2(wk[0 * FF],  wk[1 * FF]);
            bf.u[1] = pack2(wk[2 * FF],  wk[3 * FF]);
            bf.u[2] = pack2(wk[16 * FF], wk[17 * FF]);
            bf.u[3] = pack2(wk[18 * FF], wk[19 * FF]);
            #pragma unroll
            for (int rt = 0; rt < 4; ++rt)
                acc[rt][ctl] = __builtin_amdgcn_mfma_f32_16x16x32_bf16(a[rt].v, bf.v, acc[rt][ctl], 0, 0, 0);
        }
    }
    __syncthreads();   // all waves done reading A before H overwrites it

    // ---------- phase 4: h = relu(...) -> bf16 LDS [TM][264], probe-mapped ----------
    u16* H = (u16*)s_buf;
    #pragma unroll
    for (int rt = 0; rt < 4; ++rt)
        #pragma unroll
        for (int ctl = 0; ctl < 4; ++ctl)
            #pragma unroll
            for (int g = 0; g < 4; ++g) {
                int row = rt * 16 + (int)(D1[g] + 0.5f);
                int col = wvb + ctl * 16 + (int)(D2[g] + 0.5f);
                H[row * 264 + col] = f2b(fmaxf(acc[rt][ctl][g], 0.0f));
            }
    __syncthreads();

    // ---------- phase 5: GEMM2 (K=256), W2 fragments from global f32 ----------
    floatx4 acc2[4][4];
    #pragma unroll
    for (int i = 0; i < 4; ++i)
        #pragma unroll
        for (int j = 0; j < 4; ++j) acc2[i][j] = floatx4{0.f, 0.f, 0.f, 0.f};

    for (int kk = 0; kk < FF / 32; ++kk) {
        const int kb = kk * 32 + lk;
        ABFrag a[4];
        #pragma unroll
        for (int rt = 0; rt < 4; ++rt) {
            const u32* ap = (const u32*)(H + (rt * 16 + lr) * 264 + kb);
            a[rt].u[0] = ap[0]; a[rt].u[1] = ap[1];
            a[rt].u[2] = ap[8]; a[rt].u[3] = ap[9];
        }
        #pragma unroll
        for (int ctl = 0; ctl < 4; ++ctl) {
            const float* wk = w2 + (size_t)kb * FF + (wvb + ctl * 16 + lr);
            ABFrag bf;
            bf.u[0] = pack2(wk[0 * FF],  wk[1 * FF]);
            bf.u[1] = pack2(wk[2 * FF],  wk[3 * FF]);
            bf.u[2] = pack2(wk[16 * FF], wk[17 * FF]);
            bf.u[3] = pack2(wk[18 * FF], wk[19 * FF]);
            #pragma unroll
            for (int rt = 0; rt < 4; ++rt)
                acc2[rt][ctl] = __builtin_amdgcn_mfma_f32_16x16x32_bf16(a[rt].v, bf.v, acc2[rt][ctl], 0, 0, 0);
        }
    }

    // ---------- phase 6: relu -> f32 -> global, probe-mapped ----------
    float* ob = out + ((size_t)b * N1 + t0) * FF;
    #pragma unroll
    for (int rt = 0; rt < 4; ++rt)
        #pragma unroll
        for (int ctl = 0; ctl < 4; ++ctl)
            #pragma unroll
            for (int g = 0; g < 4; ++g) {
                int row = rt * 16 + (int)(D1[g] + 0.5f);
                int col = wvb + ctl * 16 + (int)(D2[g] + 0.5f);
                ob[(size_t)row * FF + col] = fmaxf(acc2[rt][ctl][g], 0.0f);
            }
}

extern "C" void kernel_launch(void* const* d_in, const int* in_sizes, int n_in,
                              void* d_out, int out_size, void* d_ws, size_t ws_size,
                              hipStream_t stream)
{
    (void)in_sizes; (void)n_in; (void)out_size; (void)d_ws; (void)ws_size;
    const float* xyz1 = (const float*)d_in[0];
    const float* xyz2 = (const float*)d_in[1];
    const float* p1   = (const float*)d_in[2];
    const float* p2   = (const float*)d_in[3];
    const float* w1   = (const float*)d_in[4];
    const float* w2   = (const float*)d_in[5];
    float* out = (float*)d_out;

    fp_fused_kernel<<<NB * TILES_PER_B, 256, 0, stream>>>(xyz1, xyz2, p1, p2, w1, w2, out);
}

// Round 7
// 96.190 us; speedup vs baseline: 1.0534x; 1.0534x over previous
//
#include <hip/hip_runtime.h>
#include <stdint.h>

typedef unsigned short u16;
typedef unsigned int   u32;

#define NB 4
#define N1 8192
#define N2 2048
#define C1 128
#define C2 256
#define KK1 384          // C2 + C1
#define FF 256
#define TM 64
#define NTHR 512
#define TILES_PER_B (N1 / TM)   // 128

typedef short short8 __attribute__((ext_vector_type(8)));
typedef float floatx4 __attribute__((ext_vector_type(4)));

union ABFrag { u32 u[4]; short8 v; };

__device__ __forceinline__ float b2f(u16 u) {
    union { u32 i; float f; } c; c.i = ((u32)u) << 16; return c.f;
}
__device__ __forceinline__ u16 f2b(float f) {
    u32 x = __float_as_uint(f);
    return (u16)((x + 0x7FFFu + ((x >> 16) & 1u)) >> 16);
}

// ---------------- prep: transpose + f32->bf16 for w1, w2 (once) ----------------
__global__ __launch_bounds__(256) void prep_kernel(
    const float* __restrict__ w1, const float* __restrict__ w2,
    u16* __restrict__ w1T, u16* __restrict__ w2T)
{
    int i = blockIdx.x * 256 + threadIdx.x;
    if (i < KK1 * FF) {            // w1T[n][k] = w1[k][n]
        int n = i / KK1, k = i - n * KK1;
        w1T[i] = f2b(w1[k * FF + n]);
    }
    int j = i - KK1 * FF;
    if (j >= 0 && j < FF * FF) {   // w2T[n][k] = w2[k][n]
        int n = j / FF, k = j - n * FF;
        w2T[j] = f2b(w2[k * FF + n]);
    }
}

// ---- fused: 3nn + interp + concat + mlp(2x); f32 in, f32 out, 8 waves ----
__global__ __launch_bounds__(NTHR) void fp_fused_kernel(
    const float* __restrict__ xyz1, const float* __restrict__ xyz2,
    const float* __restrict__ p1,   const float* __restrict__ p2,
    const u16* __restrict__ w1T,    const u16* __restrict__ w2T,
    float* __restrict__ out)
{
    __shared__ int   s_idx[TM][3];
    __shared__ float s_wt[TM][3];
    __shared__ __align__(16) char s_buf[TM * 392 * 2];   // 50176 B, multi-phase

    const int tid = threadIdx.x;
    const int b   = blockIdx.x / TILES_PER_B;
    const int t0  = (blockIdx.x % TILES_PER_B) * TM;

    // ---------- phase 1: 3-NN (8-way split per row) ----------
    float4* xp = (float4*)s_buf;                              // [N2] (x,y,z,|x|^2)
    float*  pd = (float*)(s_buf + N2 * 16);                   // [8][TM][3]
    int*    pi = (int*)  (s_buf + N2 * 16 + 8 * TM * 3 * 4);  // [8][TM][3]

    for (int j = tid; j < N2; j += NTHR) {
        const float* q = xyz2 + ((size_t)b * N2 + j) * 3;
        float x = q[0], y = q[1], z = q[2];
        float s2 = __fadd_rn(__fadd_rn(__fmul_rn(x,x), __fmul_rn(y,y)), __fmul_rn(z,z));
        xp[j] = make_float4(x, y, z, s2);
    }
    __syncthreads();

    {
        const int r = tid & 63, ch = tid >> 6;                // wave = chunk
        const float* q = xyz1 + ((size_t)b * N1 + t0 + r) * 3;
        float qx = q[0], qy = q[1], qz = q[2];
        float s1 = __fadd_rn(__fadd_rn(__fmul_rn(qx,qx), __fmul_rn(qy,qy)), __fmul_rn(qz,qz));
        float bd0 = 3e38f, bd1 = 3e38f, bd2 = 3e38f;
        int   bi0 = 0, bi1 = 0, bi2 = 0;
        const int j0 = ch * (N2 / 8);
        for (int j = j0; j < j0 + N2 / 8; ++j) {
            float4 p = xp[j];                                  // wave-uniform -> LDS broadcast
            // match np expanded form, plain mul/add (no fma contraction)
            float t  = __fadd_rn(__fadd_rn(__fmul_rn(qx,p.x), __fmul_rn(qy,p.y)), __fmul_rn(qz,p.z));
            float d  = __fsub_rn(__fadd_rn(s1, p.w), __fmul_rn(2.0f, t));
            if (d < bd2) {
                if (d < bd1) {
                    bd2 = bd1; bi2 = bi1;
                    if (d < bd0) { bd1 = bd0; bi1 = bi0; bd0 = d; bi0 = j; }
                    else         { bd1 = d;  bi1 = j; }
                } else { bd2 = d; bi2 = j; }
            }
        }
        const int o = (ch * TM + r) * 3;
        pd[o+0] = bd0; pd[o+1] = bd1; pd[o+2] = bd2;
        pi[o+0] = bi0; pi[o+1] = bi1; pi[o+2] = bi2;
    }
    __syncthreads();

    if (tid < TM) {
        float d0 = 3e38f, d1 = 3e38f, d2 = 3e38f;
        int   i0 = 0, i1 = 0, i2 = 0;
        for (int c = 0; c < 8; ++c) {                          // ascending chunk = ascending idx
            const int o = (c * TM + tid) * 3;
            #pragma unroll
            for (int k = 0; k < 3; ++k) {
                float d = pd[o + k]; int ix = pi[o + k];
                if (d < d2) {
                    if (d < d1) {
                        d2 = d1; i2 = i1;
                        if (d < d0) { d1 = d0; i1 = i0; d0 = d; i0 = ix; }
                        else        { d1 = d;  i1 = ix; }
                    } else { d2 = d; i2 = ix; }
                }
            }
        }
        d0 = fmaxf(d0, 1e-10f); d1 = fmaxf(d1, 1e-10f); d2 = fmaxf(d2, 1e-10f);
        float v0 = 1.0f / d0, v1 = 1.0f / d1, v2 = 1.0f / d2;
        float s  = 1.0f / (v0 + v1 + v2);
        s_wt[tid][0] = v0 * s; s_wt[tid][1] = v1 * s; s_wt[tid][2] = v2 * s;
        s_idx[tid][0] = i0; s_idx[tid][1] = i1; s_idx[tid][2] = i2;
    }
    __syncthreads();

    // ---------- phase 2: A tile = [interp | points1], bf16 [TM][392] ----------
    u16* A = (u16*)s_buf;
    {
        const float* pb = p2 + (size_t)b * N2 * C2;
        const int col = tid & 255;
        for (int rr = (tid >> 8); rr < TM; rr += 2) {
            float w0 = s_wt[rr][0], w1v = s_wt[rr][1], w2v = s_wt[rr][2];
            int   i0 = s_idx[rr][0], i1 = s_idx[rr][1], i2 = s_idx[rr][2];
            float acc = w0  * pb[i0 * C2 + col]
                      + w1v * pb[i1 * C2 + col]
                      + w2v * pb[i2 * C2 + col];
            A[rr * 392 + col] = f2b(acc);
        }
        const int c = tid & 127, r4 = tid >> 7;                // 0..3
        for (int rr = r4; rr < TM; rr += 4)
            A[rr * 392 + 256 + c] = f2b(p1[((size_t)b * N1 + t0 + rr) * C1 + c]);
    }
    __syncthreads();

    // ---------- phase 2.5: empirical C/D map probe (2 MFMAs) ----------
    const int lane = tid & 63;
    const int wv   = tid >> 6;          // 0..7, wave -> 32-col slice
    const int lr   = lane & 15;
    const int lg   = lane >> 4;         // k-group 0..3
    const int lk   = lg << 2;           // 0,4,8,12
    const int wvb  = wv * 32;

    int id1[4], id2[4];
    {
        u16 rbf = f2b((float)lr);        // 0..15, exact in bf16
        u16 c32 = f2b(1.0f / 32.0f);     // 2^-5, exact
        ABFrag pa, pc;
        u32 ra = (u32)rbf | ((u32)rbf << 16);
        u32 rc = (u32)c32 | ((u32)c32 << 16);
        pa.u[0] = pa.u[1] = pa.u[2] = pa.u[3] = ra;
        pc.u[0] = pc.u[1] = pc.u[2] = pc.u[3] = rc;
        floatx4 z = {0.f, 0.f, 0.f, 0.f};
        floatx4 D1 = __builtin_amdgcn_mfma_f32_16x16x32_bf16(pa.v, pc.v, z, 0, 0, 0); // row of (lane,g)
        floatx4 D2 = __builtin_amdgcn_mfma_f32_16x16x32_bf16(pc.v, pa.v, z, 0, 0, 0); // col of (lane,g)
        #pragma unroll
        for (int g = 0; g < 4; ++g) { id1[g] = (int)(D1[g] + 0.5f); id2[g] = (int)(D2[g] + 0.5f); }
    }

    // ---------- phase 3: GEMM1 (K=384), W1 from pre-packed bf16 w1T ----------
    floatx4 acc[4][2];
    #pragma unroll
    for (int i = 0; i < 4; ++i)
        #pragma unroll
        for (int j = 0; j < 2; ++j) acc[i][j] = floatx4{0.f, 0.f, 0.f, 0.f};

    for (int kk = 0; kk < KK1 / 32; ++kk) {
        const int kb = kk * 32 + lk;
        ABFrag a[4];
        #pragma unroll
        for (int rt = 0; rt < 4; ++rt) {
            const u32* ap = (const u32*)(A + (rt * 16 + lr) * 392 + kb);
            a[rt].u[0] = ap[0]; a[rt].u[1] = ap[1];
            a[rt].u[2] = ap[8]; a[rt].u[3] = ap[9];
        }
        #pragma unroll
        for (int ctl = 0; ctl < 2; ++ctl) {
            const u16* wk = w1T + (size_t)(wvb + ctl * 16 + lr) * KK1 + kb;
            ABFrag bf;
            bf.u[0] = *(const u32*)(wk);
            bf.u[1] = *(const u32*)(wk + 2);
            bf.u[2] = *(const u32*)(wk + 16);
            bf.u[3] = *(const u32*)(wk + 18);
            #pragma unroll
            for (int rt = 0; rt < 4; ++rt)
                acc[rt][ctl] = __builtin_amdgcn_mfma_f32_16x16x32_bf16(a[rt].v, bf.v, acc[rt][ctl], 0, 0, 0);
        }
    }
    __syncthreads();   // all waves done reading A before H overwrites it

    // ---------- phase 4: h = relu(...) -> bf16 LDS [TM][264], probe-mapped ----------
    u16* H = (u16*)s_buf;
    #pragma unroll
    for (int rt = 0; rt < 4; ++rt)
        #pragma unroll
        for (int ctl = 0; ctl < 2; ++ctl)
            #pragma unroll
            for (int g = 0; g < 4; ++g) {
                int row = rt * 16 + id1[g];
                int col = wvb + ctl * 16 + id2[g];
                H[row * 264 + col] = f2b(fmaxf(acc[rt][ctl][g], 0.0f));
            }
    __syncthreads();

    // ---------- phase 5: GEMM2 (K=256), W2 from pre-packed bf16 w2T ----------
    floatx4 acc2[4][2];
    #pragma unroll
    for (int i = 0; i < 4; ++i)
        #pragma unroll
        for (int j = 0; j < 2; ++j) acc2[i][j] = floatx4{0.f, 0.f, 0.f, 0.f};

    for (int kk = 0; kk < FF / 32; ++kk) {
        const int kb = kk * 32 + lk;
        ABFrag a[4];
        #pragma unroll
        for (int rt = 0; rt < 4; ++rt) {
            const u32* ap = (const u32*)(H + (rt * 16 + lr) * 264 + kb);
            a[rt].u[0] = ap[0]; a[rt].u[1] = ap[1];
            a[rt].u[2] = ap[8]; a[rt].u[3] = ap[9];
        }
        #pragma unroll
        for (int ctl = 0; ctl < 2; ++ctl) {
            const u16* wk = w2T + (size_t)(wvb + ctl * 16 + lr) * FF + kb;
            ABFrag bf;
            bf.u[0] = *(const u32*)(wk);
            bf.u[1] = *(const u32*)(wk + 2);
            bf.u[2] = *(const u32*)(wk + 16);
            bf.u[3] = *(const u32*)(wk + 18);
            #pragma unroll
            for (int rt = 0; rt < 4; ++rt)
                acc2[rt][ctl] = __builtin_amdgcn_mfma_f32_16x16x32_bf16(a[rt].v, bf.v, acc2[rt][ctl], 0, 0, 0);
        }
    }

    // ---------- phase 6: relu -> f32 -> global, probe-mapped ----------
    float* ob = out + ((size_t)b * N1 + t0) * FF;
    #pragma unroll
    for (int rt = 0; rt < 4; ++rt)
        #pragma unroll
        for (int ctl = 0; ctl < 2; ++ctl)
            #pragma unroll
            for (int g = 0; g < 4; ++g) {
                int row = rt * 16 + id1[g];
                int col = wvb + ctl * 16 + id2[g];
                ob[(size_t)row * FF + col] = fmaxf(acc2[rt][ctl][g], 0.0f);
            }
}

extern "C" void kernel_launch(void* const* d_in, const int* in_sizes, int n_in,
                              void* d_out, int out_size, void* d_ws, size_t ws_size,
                              hipStream_t stream)
{
    (void)in_sizes; (void)n_in; (void)out_size; (void)ws_size;
    const float* xyz1 = (const float*)d_in[0];
    const float* xyz2 = (const float*)d_in[1];
    const float* p1   = (const float*)d_in[2];
    const float* p2   = (const float*)d_in[3];
    const float* w1   = (const float*)d_in[4];
    const float* w2   = (const float*)d_in[5];
    float* out = (float*)d_out;

    u16* w1T = (u16*)d_ws;            // [256][384] bf16
    u16* w2T = w1T + KK1 * FF;        // [256][256] bf16

    prep_kernel<<<(KK1 * FF + FF * FF + 255) / 256, 256, 0, stream>>>(w1, w2, w1T, w2T);
    fp_fused_kernel<<<NB * TILES_PER_B, NTHR, 0, stream>>>(xyz1, xyz2, p1, p2, w1T, w2T, out);
}

// Round 8
// 82.602 us; speedup vs baseline: 1.2266x; 1.1645x over previous
//
#include <hip/hip_runtime.h>
#include <stdint.h>

typedef unsigned short u16;
typedef unsigned int   u32;

#define NB 4
#define N1 8192
#define N2 2048
#define C1 128
#define C2 256
#define KK1 384          // C2 + C1
#define FF 256
#define TM 64
#define NTHR 1024
#define NCH 16
#define CHSZ (N2 / NCH)  // 128
#define TILES_PER_B (N1 / TM)   // 128

typedef short short8 __attribute__((ext_vector_type(8)));
typedef float floatx4 __attribute__((ext_vector_type(4)));

union ABFrag { u32 u[4]; short8 v; };

__device__ __forceinline__ float b2f(u16 u) {
    union { u32 i; float f; } c; c.i = ((u32)u) << 16; return c.f;
}
__device__ __forceinline__ u16 f2b(float f) {
    u32 x = __float_as_uint(f);
    return (u16)((x + 0x7FFFu + ((x >> 16) & 1u)) >> 16);
}

// ---------------- prep: transpose + f32->bf16 for w1, w2 (once) ----------------
__global__ __launch_bounds__(256) void prep_kernel(
    const float* __restrict__ w1, const float* __restrict__ w2,
    u16* __restrict__ w1T, u16* __restrict__ w2T)
{
    int i = blockIdx.x * 256 + threadIdx.x;
    if (i < KK1 * FF) {            // w1T[n][k] = w1[k][n]
        int n = i / KK1, k = i - n * KK1;
        w1T[i] = f2b(w1[k * FF + n]);
    }
    int j = i - KK1 * FF;
    if (j >= 0 && j < FF * FF) {   // w2T[n][k] = w2[k][n]
        int n = j / FF, k = j - n * FF;
        w2T[j] = f2b(w2[k * FF + n]);
    }
}

// ---- fused: 3nn + interp + concat + mlp(2x); f32 in, f32 out, 16 waves ----
__global__ __launch_bounds__(NTHR, 8) void fp_fused_kernel(
    const float* __restrict__ xyz1, const float* __restrict__ xyz2,
    const float* __restrict__ p1,   const float* __restrict__ p2,
    const u16* __restrict__ w1T,    const u16* __restrict__ w2T,
    float* __restrict__ out)
{
    __shared__ int   s_idx[TM][3];
    __shared__ float s_wt[TM][3];
    // phase1: xp 32768 + pd 12288 + pi 12288 = 57344 ; phase2+: A 49152 ; H 33792
    __shared__ __align__(16) char s_buf[57344];

    const int tid = threadIdx.x;
    const int b   = blockIdx.x / TILES_PER_B;
    const int t0  = (blockIdx.x % TILES_PER_B) * TM;

    // ---------- phase 1: 3-NN (16-way split per row) ----------
    float4* xp = (float4*)s_buf;                               // [N2] (x,y,z,|x|^2)
    float*  pd = (float*)(s_buf + N2 * 16);                    // [NCH][TM][3]
    int*    pi = (int*)  (s_buf + N2 * 16 + NCH * TM * 3 * 4); // [NCH][TM][3]

    for (int j = tid; j < N2; j += NTHR) {
        const float* q = xyz2 + ((size_t)b * N2 + j) * 3;
        float x = q[0], y = q[1], z = q[2];
        float s2 = __fadd_rn(__fadd_rn(__fmul_rn(x,x), __fmul_rn(y,y)), __fmul_rn(z,z));
        xp[j] = make_float4(x, y, z, s2);
    }
    __syncthreads();

    {
        const int r = tid & 63, ch = tid >> 6;                 // wave = chunk 0..15
        const float* q = xyz1 + ((size_t)b * N1 + t0 + r) * 3;
        float qx = q[0], qy = q[1], qz = q[2];
        float s1 = __fadd_rn(__fadd_rn(__fmul_rn(qx,qx), __fmul_rn(qy,qy)), __fmul_rn(qz,qz));
        float bd0 = 3e38f, bd1 = 3e38f, bd2 = 3e38f;
        int   bi0 = 0, bi1 = 0, bi2 = 0;
        const int j0 = ch * CHSZ;
        #pragma unroll 4
        for (int j = j0; j < j0 + CHSZ; ++j) {
            float4 p = xp[j];                                  // wave-uniform -> LDS broadcast
            // match np expanded form, plain mul/add (no fma contraction)
            float t  = __fadd_rn(__fadd_rn(__fmul_rn(qx,p.x), __fmul_rn(qy,p.y)), __fmul_rn(qz,p.z));
            float d  = __fsub_rn(__fadd_rn(s1, p.w), __fmul_rn(2.0f, t));
            // branchless exact top-3 (strict < : ties keep lowest index)
            float nb0 = fminf(d, bd0);
            float nb1 = __builtin_amdgcn_fmed3f(d, bd0, bd1);
            float nb2 = __builtin_amdgcn_fmed3f(d, bd1, bd2);
            bool c0 = d < bd0, c1 = d < bd1, c2 = d < bd2;
            int t01 = c0 ? bi0 : j;
            bi0     = c0 ? j   : bi0;
            int t12 = c1 ? bi1 : j;
            bi1     = c1 ? t01 : bi1;
            bi2     = c2 ? t12 : bi2;
            bd0 = nb0; bd1 = nb1; bd2 = nb2;
        }
        const int o = (ch * TM + r) * 3;
        pd[o+0] = bd0; pd[o+1] = bd1; pd[o+2] = bd2;
        pi[o+0] = bi0; pi[o+1] = bi1; pi[o+2] = bi2;
    }
    __syncthreads();

    if (tid < TM) {
        float d0 = 3e38f, d1 = 3e38f, d2 = 3e38f;
        int   i0 = 0, i1 = 0, i2 = 0;
        for (int c = 0; c < NCH; ++c) {                        // ascending chunk = ascending idx
            const int o = (c * TM + tid) * 3;
            #pragma unroll
            for (int k = 0; k < 3; ++k) {
                float d = pd[o + k]; int ix = pi[o + k];
                if (d < d2) {
                    if (d < d1) {
                        d2 = d1; i2 = i1;
                        if (d < d0) { d1 = d0; i1 = i0; d0 = d; i0 = ix; }
                        else        { d1 = d;  i1 = ix; }
                    } else { d2 = d; i2 = ix; }
                }
            }
        }
        d0 = fmaxf(d0, 1e-10f); d1 = fmaxf(d1, 1e-10f); d2 = fmaxf(d2, 1e-10f);
        float v0 = 1.0f / d0, v1 = 1.0f / d1, v2 = 1.0f / d2;
        float s  = 1.0f / (v0 + v1 + v2);
        s_wt[tid][0] = v0 * s; s_wt[tid][1] = v1 * s; s_wt[tid][2] = v2 * s;
        s_idx[tid][0] = i0; s_idx[tid][1] = i1; s_idx[tid][2] = i2;
    }
    __syncthreads();

    // ---------- phase 2: A tile = [interp | points1], bf16 [TM][392] ----------
    u16* A = (u16*)s_buf;
    {
        const float* pb = p2 + (size_t)b * N2 * C2;
        const int col = tid & 255;
        for (int rr = (tid >> 8); rr < TM; rr += 4) {
            float w0 = s_wt[rr][0], w1v = s_wt[rr][1], w2v = s_wt[rr][2];
            int   i0 = s_idx[rr][0], i1 = s_idx[rr][1], i2 = s_idx[rr][2];
            float acc = w0  * pb[i0 * C2 + col]
                      + w1v * pb[i1 * C2 + col]
                      + w2v * pb[i2 * C2 + col];
            A[rr * 392 + col] = f2b(acc);
        }
        const int c = tid & 127, r8 = tid >> 7;                // 0..7
        for (int rr = r8; rr < TM; rr += 8)
            A[rr * 392 + 256 + c] = f2b(p1[((size_t)b * N1 + t0 + rr) * C1 + c]);
    }
    __syncthreads();

    // ---------- phase 2.5: empirical C/D map probe (2 MFMAs) ----------
    const int lane = tid & 63;
    const int wv   = tid >> 6;          // 0..15, wave -> 16-col slice
    const int lr   = lane & 15;
    const int lg   = lane >> 4;         // k-group 0..3
    const int lk   = lg << 2;           // 0,4,8,12
    const int wvb  = wv * 16;

    int id1[4], id2[4];
    {
        u16 rbf = f2b((float)lr);        // 0..15, exact in bf16
        u16 c32 = f2b(1.0f / 32.0f);     // 2^-5, exact
        ABFrag pa, pc;
        u32 ra = (u32)rbf | ((u32)rbf << 16);
        u32 rc = (u32)c32 | ((u32)c32 << 16);
        pa.u[0] = pa.u[1] = pa.u[2] = pa.u[3] = ra;
        pc.u[0] = pc.u[1] = pc.u[2] = pc.u[3] = rc;
        floatx4 z = {0.f, 0.f, 0.f, 0.f};
        floatx4 D1 = __builtin_amdgcn_mfma_f32_16x16x32_bf16(pa.v, pc.v, z, 0, 0, 0); // row of (lane,g)
        floatx4 D2 = __builtin_amdgcn_mfma_f32_16x16x32_bf16(pc.v, pa.v, z, 0, 0, 0); // col of (lane,g)
        #pragma unroll
        for (int g = 0; g < 4; ++g) { id1[g] = (int)(D1[g] + 0.5f); id2[g] = (int)(D2[g] + 0.5f); }
    }

    // ---------- phase 3: GEMM1 (K=384), W1 from pre-packed bf16 w1T ----------
    floatx4 acc[4];
    #pragma unroll
    for (int i = 0; i < 4; ++i) acc[i] = floatx4{0.f, 0.f, 0.f, 0.f};

    for (int kk = 0; kk < KK1 / 32; ++kk) {
        const int kb = kk * 32 + lk;
        ABFrag a[4];
        #pragma unroll
        for (int rt = 0; rt < 4; ++rt) {
            const u32* ap = (const u32*)(A + (rt * 16 + lr) * 392 + kb);
            a[rt].u[0] = ap[0]; a[rt].u[1] = ap[1];
            a[rt].u[2] = ap[8]; a[rt].u[3] = ap[9];
        }
        const u16* wk = w1T + (size_t)(wvb + lr) * KK1 + kb;
        ABFrag bf;
        bf.u[0] = *(const u32*)(wk);
        bf.u[1] = *(const u32*)(wk + 2);
        bf.u[2] = *(const u32*)(wk + 16);
        bf.u[3] = *(const u32*)(wk + 18);
        #pragma unroll
        for (int rt = 0; rt < 4; ++rt)
            acc[rt] = __builtin_amdgcn_mfma_f32_16x16x32_bf16(a[rt].v, bf.v, acc[rt], 0, 0, 0);
    }
    __syncthreads();   // all waves done reading A before H overwrites it

    // ---------- phase 4: h = relu(...) -> bf16 LDS [TM][264], probe-mapped ----------
    u16* H = (u16*)s_buf;
    #pragma unroll
    for (int rt = 0; rt < 4; ++rt)
        #pragma unroll
        for (int g = 0; g < 4; ++g) {
            int row = rt * 16 + id1[g];
            int col = wvb + id2[g];
            H[row * 264 + col] = f2b(fmaxf(acc[rt][g], 0.0f));
        }
    __syncthreads();

    // ---------- phase 5: GEMM2 (K=256), W2 from pre-packed bf16 w2T ----------
    floatx4 acc2[4];
    #pragma unroll
    for (int i = 0; i < 4; ++i) acc2[i] = floatx4{0.f, 0.f, 0.f, 0.f};

    for (int kk = 0; kk < FF / 32; ++kk) {
        const int kb = kk * 32 + lk;
        ABFrag a[4];
        #pragma unroll
        for (int rt = 0; rt < 4; ++rt) {
            const u32* ap = (const u32*)(H + (rt * 16 + lr) * 264 + kb);
            a[rt].u[0] = ap[0]; a[rt].u[1] = ap[1];
            a[rt].u[2] = ap[8]; a[rt].u[3] = ap[9];
        }
        const u16* wk = w2T + (size_t)(wvb + lr) * FF + kb;
        ABFrag bf;
        bf.u[0] = *(const u32*)(wk);
        bf.u[1] = *(const u32*)(wk + 2);
        bf.u[2] = *(const u32*)(wk + 16);
        bf.u[3] = *(const u32*)(wk + 18);
        #pragma unroll
        for (int rt = 0; rt < 4; ++rt)
            acc2[rt] = __builtin_amdgcn_mfma_f32_16x16x32_bf16(a[rt].v, bf.v, acc2[rt], 0, 0, 0);
    }

    // ---------- phase 6: relu -> f32 -> global, probe-mapped ----------
    float* ob = out + ((size_t)b * N1 + t0) * FF;
    #pragma unroll
    for (int rt = 0; rt < 4; ++rt)
        #pragma unroll
        for (int g = 0; g < 4; ++g) {
            int row = rt * 16 + id1[g];
            int col = wvb + id2[g];
            ob[(size_t)row * FF + col] = fmaxf(acc2[rt][g], 0.0f);
        }
}

extern "C" void kernel_launch(void* const* d_in, const int* in_sizes, int n_in,
                              void* d_out, int out_size, void* d_ws, size_t ws_size,
                              hipStream_t stream)
{
    (void)in_sizes; (void)n_in; (void)out_size; (void)ws_size;
    const float* xyz1 = (const float*)d_in[0];
    const float* xyz2 = (const float*)d_in[1];
    const float* p1   = (const float*)d_in[2];
    const float* p2   = (const float*)d_in[3];
    const float* w1   = (const float*)d_in[4];
    const float* w2   = (const float*)d_in[5];
    float* out = (float*)d_out;

    u16* w1T = (u16*)d_ws;            // [256][384] bf16
    u16* w2T = w1T + KK1 * FF;        // [256][256] bf16

    prep_kernel<<<(KK1 * FF + FF * FF + 255) / 256, 256, 0, stream>>>(w1, w2, w1T, w2T);
    fp_fused_kernel<<<NB * TILES_PER_B, NTHR, 0, stream>>>(xyz1, xyz2, p1, p2, w1T, w2T, out);
}

// Round 9
// 70.689 us; speedup vs baseline: 1.4334x; 1.1685x over previous
//
#include <hip/hip_runtime.h>
#include <stdint.h>

typedef unsigned short u16;
typedef unsigned int   u32;

#define NB 4
#define N1 8192
#define N2 2048
#define C1 128
#define C2 256
#define KK1 384          // C2 + C1
#define FF 256
#define TM 64
#define NTHR 1024
#define NCH 16
#define CHSZ (N2 / NCH)  // 128
#define TILES_PER_B (N1 / TM)   // 128
#define APAD 394         // u16 stride; 788B/4 = 197 ≡ 5 (mod 32) -> conflict-free
#define HPAD 266         // 532B/4 = 133 ≡ 5 (mod 32)
#define NKT1 (KK1 / 32)  // 12
#define NKT2 (FF / 32)   // 8

typedef short short8 __attribute__((ext_vector_type(8)));
typedef float floatx4 __attribute__((ext_vector_type(4)));
typedef u32   u32x4  __attribute__((ext_vector_type(4)));

union ABFrag { u32 u[4]; short8 v; u32x4 q; };

__device__ __forceinline__ u16 f2b(float f) {
    u32 x = __float_as_uint(f);
    return (u16)((x + 0x7FFFu + ((x >> 16) & 1u)) >> 16);
}
__device__ __forceinline__ u32 pack2(float a, float b) {
    return (u32)f2b(a) | ((u32)f2b(b) << 16);
}

// ---- prep: weight fragments (per-lane swizzled) + xp table (x,y,z,|x|^2) ----
__global__ __launch_bounds__(256) void prep_kernel(
    const float* __restrict__ w1, const float* __restrict__ w2,
    const float* __restrict__ xyz2,
    u32x4* __restrict__ w1F, u32x4* __restrict__ w2F, float4* __restrict__ xp)
{
    int i = blockIdx.x * 256 + threadIdx.x;
    if (i < 16 * NKT1 * 64) {                       // w1 fragments [nt][kt][lane]
        int nt = i / (NKT1 * 64), rem = i % (NKT1 * 64);
        int kt = rem / 64, lane = rem % 64;
        int n  = nt * 16 + (lane & 15);
        int k0 = kt * 32 + (lane >> 4) * 4;
        const float* wc = w1 + n;                   // column n, stride FF
        ABFrag f;
        f.u[0] = pack2(wc[(k0 + 0) * FF],  wc[(k0 + 1) * FF]);
        f.u[1] = pack2(wc[(k0 + 2) * FF],  wc[(k0 + 3) * FF]);
        f.u[2] = pack2(wc[(k0 + 16) * FF], wc[(k0 + 17) * FF]);
        f.u[3] = pack2(wc[(k0 + 18) * FF], wc[(k0 + 19) * FF]);
        w1F[i] = f.q;
        return;
    }
    i -= 16 * NKT1 * 64;
    if (i < 16 * NKT2 * 64) {                       // w2 fragments
        int nt = i / (NKT2 * 64), rem = i % (NKT2 * 64);
        int kt = rem / 64, lane = rem % 64;
        int n  = nt * 16 + (lane & 15);
        int k0 = kt * 32 + (lane >> 4) * 4;
        const float* wc = w2 + n;
        ABFrag f;
        f.u[0] = pack2(wc[(k0 + 0) * FF],  wc[(k0 + 1) * FF]);
        f.u[1] = pack2(wc[(k0 + 2) * FF],  wc[(k0 + 3) * FF]);
        f.u[2] = pack2(wc[(k0 + 16) * FF], wc[(k0 + 17) * FF]);
        f.u[3] = pack2(wc[(k0 + 18) * FF], wc[(k0 + 19) * FF]);
        w2F[i] = f.q;
        return;
    }
    i -= 16 * NKT2 * 64;
    if (i < NB * N2) {                              // xp table
        const float* q = xyz2 + (size_t)i * 3;
        float x = q[0], y = q[1], z = q[2];
        float s2 = __fadd_rn(__fadd_rn(__fmul_rn(x,x), __fmul_rn(y,y)), __fmul_rn(z,z));
        xp[i] = make_float4(x, y, z, s2);
    }
}

// ---- fused: 3nn + interp + concat + mlp(2x); f32 in, f32 out, 16 waves ----
__global__ __launch_bounds__(NTHR, 8) void fp_fused_kernel(
    const float* __restrict__ xyz1, const float* __restrict__ p1,
    const float* __restrict__ p2,
    const u32x4* __restrict__ w1F,  const u32x4* __restrict__ w2F,
    const float4* __restrict__ xp,  float* __restrict__ out)
{
    __shared__ int   s_idx[TM][3];
    __shared__ float s_wt[TM][3];
    // phase1: pd 12288 + pi 12288 ; phase2+: A [TM][APAD] bf16 = 50432 ; H = 34048
    __shared__ __align__(16) char s_buf[TM * APAD * 2];

    const int tid = threadIdx.x;
    const int b   = blockIdx.x / TILES_PER_B;
    const int t0  = (blockIdx.x % TILES_PER_B) * TM;

    float* pd = (float*)s_buf;                     // [NCH][TM][3]
    int*   pi = (int*)(s_buf + NCH * TM * 3 * 4);  // [NCH][TM][3]

    // ---------- phase 1: 3-NN scan, points via wave-uniform (scalar) loads ----------
    {
        const int r  = tid & 63;
        const int ch = __builtin_amdgcn_readfirstlane(tid >> 6);   // wave-uniform chunk
        const float4* cb = xp + (size_t)b * N2 + ch * CHSZ;
        const float* q = xyz1 + ((size_t)b * N1 + t0 + r) * 3;
        float qx = q[0], qy = q[1], qz = q[2];
        float s1 = __fadd_rn(__fadd_rn(__fmul_rn(qx,qx), __fmul_rn(qy,qy)), __fmul_rn(qz,qz));
        float bd0 = 3e38f, bd1 = 3e38f, bd2 = 3e38f;
        int   bi0 = 0, bi1 = 0, bi2 = 0;
        const int j0 = ch * CHSZ;
        #pragma unroll 8
        for (int jj = 0; jj < CHSZ; ++jj) {
            float4 p = cb[jj];
            // match np expanded form, plain mul/add (no fma contraction)
            float t  = __fadd_rn(__fadd_rn(__fmul_rn(qx,p.x), __fmul_rn(qy,p.y)), __fmul_rn(qz,p.z));
            float d  = __fsub_rn(__fadd_rn(s1, p.w), __fmul_rn(2.0f, t));
            // branchless exact top-3 (strict < : ties keep lowest index)
            float nb0 = fminf(d, bd0);
            float nb1 = __builtin_amdgcn_fmed3f(d, bd0, bd1);
            float nb2 = __builtin_amdgcn_fmed3f(d, bd1, bd2);
            bool c0 = d < bd0, c1 = d < bd1, c2 = d < bd2;
            int j  = j0 + jj;
            int t01 = c0 ? bi0 : j;
            bi0     = c0 ? j   : bi0;
            int t12 = c1 ? bi1 : j;
            bi1     = c1 ? t01 : bi1;
            bi2     = c2 ? t12 : bi2;
            bd0 = nb0; bd1 = nb1; bd2 = nb2;
        }
        const int o = (ch * TM + r) * 3;
        pd[o+0] = bd0; pd[o+1] = bd1; pd[o+2] = bd2;
        pi[o+0] = bi0; pi[o+1] = bi1; pi[o+2] = bi2;
    }
    __syncthreads();

    // ---------- merge (branchless; ascending chunk order = ascending index) ----------
    if (tid < TM) {
        float d0 = 3e38f, d1 = 3e38f, d2 = 3e38f;
        int   i0 = 0, i1 = 0, i2 = 0;
        for (int c = 0; c < NCH; ++c) {
            const int o = (c * TM + tid) * 3;
            #pragma unroll
            for (int k = 0; k < 3; ++k) {
                float d = pd[o + k]; int ix = pi[o + k];
                float n0 = fminf(d, d0);
                float n1 = __builtin_amdgcn_fmed3f(d, d0, d1);
                float n2 = __builtin_amdgcn_fmed3f(d, d1, d2);
                bool c0 = d < d0, c1 = d < d1, c2 = d < d2;
                int t01 = c0 ? i0 : ix;
                i0      = c0 ? ix : i0;
                int t12 = c1 ? i1 : t01;
                i1      = c1 ? t01 : i1;
                i2      = c2 ? t12 : i2;
                d0 = n0; d1 = n1; d2 = n2;
            }
        }
        d0 = fmaxf(d0, 1e-10f); d1 = fmaxf(d1, 1e-10f); d2 = fmaxf(d2, 1e-10f);
        float v0 = 1.0f / d0, v1 = 1.0f / d1, v2 = 1.0f / d2;
        float s  = 1.0f / (v0 + v1 + v2);
        s_wt[tid][0] = v0 * s; s_wt[tid][1] = v1 * s; s_wt[tid][2] = v2 * s;
        s_idx[tid][0] = i0; s_idx[tid][1] = i1; s_idx[tid][2] = i2;
    }
    __syncthreads();

    // ---------- phase 2: A tile = [interp | points1], bf16 [TM][APAD] ----------
    u16* A = (u16*)s_buf;
    {
        const float* pb = p2 + (size_t)b * N2 * C2;
        const int col2 = (tid & 127) * 2;
        for (int rr = (tid >> 7); rr < TM; rr += 8) {
            float w0 = s_wt[rr][0], w1v = s_wt[rr][1], w2v = s_wt[rr][2];
            int   i0 = s_idx[rr][0], i1 = s_idx[rr][1], i2 = s_idx[rr][2];
            float2 a0 = *(const float2*)(pb + (size_t)i0 * C2 + col2);
            float2 a1 = *(const float2*)(pb + (size_t)i1 * C2 + col2);
            float2 a2 = *(const float2*)(pb + (size_t)i2 * C2 + col2);
            float e0 = w0 * a0.x + w1v * a1.x + w2v * a2.x;
            float e1 = w0 * a0.y + w1v * a1.y + w2v * a2.y;
            *(u32*)(A + rr * APAD + col2) = pack2(e0, e1);
        }
        const int c4 = (tid & 31) * 4, r32 = tid >> 5;   // 0..31
        #pragma unroll
        for (int rv = 0; rv < 2; ++rv) {
            int rr = r32 + rv * 32;
            float4 v = *(const float4*)(p1 + ((size_t)b * N1 + t0 + rr) * C1 + c4);
            u32* w = (u32*)(A + rr * APAD + 256 + c4);
            w[0] = pack2(v.x, v.y);
            w[1] = pack2(v.z, v.w);
        }
    }
    __syncthreads();

    // ---------- phase 2.5: empirical C/D map probe (2 MFMAs) ----------
    const int lane = tid & 63;
    const int wv   = tid >> 6;          // 0..15, wave -> 16-col slice
    const int lr   = lane & 15;
    const int lg   = lane >> 4;         // k-group 0..3
    const int lk   = lg << 2;           // 0,4,8,12
    const int wvb  = wv * 16;

    int id1[4], id2[4];
    {
        u16 rbf = f2b((float)lr);        // 0..15, exact in bf16
        u16 c32 = f2b(1.0f / 32.0f);     // 2^-5, exact
        ABFrag pa, pc;
        u32 ra = (u32)rbf | ((u32)rbf << 16);
        u32 rc = (u32)c32 | ((u32)c32 << 16);
        pa.u[0] = pa.u[1] = pa.u[2] = pa.u[3] = ra;
        pc.u[0] = pc.u[1] = pc.u[2] = pc.u[3] = rc;
        floatx4 z = {0.f, 0.f, 0.f, 0.f};
        floatx4 D1 = __builtin_amdgcn_mfma_f32_16x16x32_bf16(pa.v, pc.v, z, 0, 0, 0); // row of (lane,g)
        floatx4 D2 = __builtin_amdgcn_mfma_f32_16x16x32_bf16(pc.v, pa.v, z, 0, 0, 0); // col of (lane,g)
        #pragma unroll
        for (int g = 0; g < 4; ++g) { id1[g] = (int)(D1[g] + 0.5f); id2[g] = (int)(D2[g] + 0.5f); }
    }

    // ---------- phase 3: GEMM1 (K=384), weights as coalesced fragments ----------
    floatx4 acc[4];
    #pragma unroll
    for (int i = 0; i < 4; ++i) acc[i] = floatx4{0.f, 0.f, 0.f, 0.f};

    {
        const u32x4* wf = w1F + (size_t)(wv * NKT1) * 64 + lane;
        for (int kk = 0; kk < NKT1; ++kk) {
            const int kb = kk * 32 + lk;
            ABFrag bf; bf.q = wf[(size_t)kk * 64];
            ABFrag a[4];
            #pragma unroll
            for (int rt = 0; rt < 4; ++rt) {
                const u32* ap = (const u32*)(A + (rt * 16 + lr) * APAD + kb);
                a[rt].u[0] = ap[0]; a[rt].u[1] = ap[1];
                a[rt].u[2] = ap[8]; a[rt].u[3] = ap[9];
            }
            #pragma unroll
            for (int rt = 0; rt < 4; ++rt)
                acc[rt] = __builtin_amdgcn_mfma_f32_16x16x32_bf16(a[rt].v, bf.v, acc[rt], 0, 0, 0);
        }
    }
    __syncthreads();   // all waves done reading A before H overwrites it

    // ---------- phase 4: h = relu(...) -> bf16 LDS [TM][HPAD], probe-mapped ----------
    u16* H = (u16*)s_buf;
    #pragma unroll
    for (int rt = 0; rt < 4; ++rt)
        #pragma unroll
        for (int g = 0; g < 4; ++g) {
            int row = rt * 16 + id1[g];
            int col = wvb + id2[g];
            H[row * HPAD + col] = f2b(fmaxf(acc[rt][g], 0.0f));
        }
    __syncthreads();

    // ---------- phase 5: GEMM2 (K=256) ----------
    floatx4 acc2[4];
    #pragma unroll
    for (int i = 0; i < 4; ++i) acc2[i] = floatx4{0.f, 0.f, 0.f, 0.f};

    {
        const u32x4* wf = w2F + (size_t)(wv * NKT2) * 64 + lane;
        for (int kk = 0; kk < NKT2; ++kk) {
            const int kb = kk * 32 + lk;
            ABFrag bf; bf.q = wf[(size_t)kk * 64];
            ABFrag a[4];
            #pragma unroll
            for (int rt = 0; rt < 4; ++rt) {
                const u32* ap = (const u32*)(H + (rt * 16 + lr) * HPAD + kb);
                a[rt].u[0] = ap[0]; a[rt].u[1] = ap[1];
                a[rt].u[2] = ap[8]; a[rt].u[3] = ap[9];
            }
            #pragma unroll
            for (int rt = 0; rt < 4; ++rt)
                acc2[rt] = __builtin_amdgcn_mfma_f32_16x16x32_bf16(a[rt].v, bf.v, acc2[rt], 0, 0, 0);
        }
    }

    // ---------- phase 6: relu -> f32 -> global, probe-mapped ----------
    float* ob = out + ((size_t)b * N1 + t0) * FF;
    #pragma unroll
    for (int rt = 0; rt < 4; ++rt)
        #pragma unroll
        for (int g = 0; g < 4; ++g) {
            int row = rt * 16 + id1[g];
            int col = wvb + id2[g];
            ob[(size_t)row * FF + col] = fmaxf(acc2[rt][g], 0.0f);
        }
}

extern "C" void kernel_launch(void* const* d_in, const int* in_sizes, int n_in,
                              void* d_out, int out_size, void* d_ws, size_t ws_size,
                              hipStream_t stream)
{
    (void)in_sizes; (void)n_in; (void)out_size; (void)ws_size;
    const float* xyz1 = (const float*)d_in[0];
    const float* xyz2 = (const float*)d_in[1];
    const float* p1   = (const float*)d_in[2];
    const float* p2   = (const float*)d_in[3];
    const float* w1   = (const float*)d_in[4];
    const float* w2   = (const float*)d_in[5];
    float* out = (float*)d_out;

    u32x4*  w1F = (u32x4*)d_ws;                        // 16*12*64 frags = 196608 B
    u32x4*  w2F = w1F + 16 * NKT1 * 64;                // 16*8*64  frags = 131072 B
    float4* xpw = (float4*)(w2F + 16 * NKT2 * 64);     // 8192 float4    = 131072 B

    int prep_items = 16 * NKT1 * 64 + 16 * NKT2 * 64 + NB * N2;
    prep_kernel<<<(prep_items + 255) / 256, 256, 0, stream>>>(w1, w2, xyz2, w1F, w2F, xpw);
    fp_fused_kernel<<<NB * TILES_PER_B, NTHR, 0, stream>>>(xyz1, p1, p2, w1F, w2F, xpw, out);
}

// Round 10
// 62.755 us; speedup vs baseline: 1.6146x; 1.1264x over previous
//
#include <hip/hip_runtime.h>
#include <stdint.h>

typedef unsigned short u16;
typedef unsigned int   u32;

#define NB 4
#define N1 8192
#define N2 2048
#define C1 128
#define C2 256
#define KK1 384          // C2 + C1
#define FF 256
#define TM 64
#define NTHR 1024
#define NCH 16
#define CHSZ (N2 / NCH)  // 128 points = 64 pairs
#define TILES_PER_B (N1 / TM)   // 128
#define APAD 400         // u16; 800B/row -> 16B aligned, 50 quads ≡ 2 (mod 8): uniform quad-banks
#define HPAD 272         // u16; 544B/row -> 16B aligned, 34 quads ≡ 2 (mod 8)
#define NKT1 (KK1 / 32)  // 12
#define NKT2 (FF / 32)   // 8
#define ABYTES (TM * APAD * 2)            // 51200
#define PDOFF  ABYTES                     // pd at +51200
#define PIOFF  (ABYTES + NCH * TM * 3 * 4)

typedef short short8 __attribute__((ext_vector_type(8)));
typedef float floatx4 __attribute__((ext_vector_type(4)));
typedef float f32x2  __attribute__((ext_vector_type(2)));
typedef u32   u32x4  __attribute__((ext_vector_type(4)));

union ABFrag { u32 u[4]; short8 v; u32x4 q; };

__device__ __forceinline__ u16 f2b(float f) {
    u32 x = __float_as_uint(f);
    return (u16)((x + 0x7FFFu + ((x >> 16) & 1u)) >> 16);
}
__device__ __forceinline__ u32 pack2(float a, float b) {
    return (u32)f2b(a) | ((u32)f2b(b) << 16);
}

// ---- prep: contiguous-k weight fragments + paired (-2x,-2y,-2z,|x|^2) table ----
__global__ __launch_bounds__(256) void prep_kernel(
    const float* __restrict__ w1, const float* __restrict__ w2,
    const float* __restrict__ xyz2,
    u32x4* __restrict__ w1F, u32x4* __restrict__ w2F, float* __restrict__ xq)
{
    int i = blockIdx.x * 256 + threadIdx.x;
    if (i < 16 * NKT1 * 64) {                       // w1 fragments [nt][kt][lane], k = k0..k0+7
        int nt = i / (NKT1 * 64), rem = i % (NKT1 * 64);
        int kt = rem / 64, lane = rem % 64;
        int n  = nt * 16 + (lane & 15);
        int k0 = kt * 32 + (lane >> 4) * 8;
        const float* wc = w1 + n;                   // column n, stride FF
        ABFrag f;
        f.u[0] = pack2(wc[(k0 + 0) * FF], wc[(k0 + 1) * FF]);
        f.u[1] = pack2(wc[(k0 + 2) * FF], wc[(k0 + 3) * FF]);
        f.u[2] = pack2(wc[(k0 + 4) * FF], wc[(k0 + 5) * FF]);
        f.u[3] = pack2(wc[(k0 + 6) * FF], wc[(k0 + 7) * FF]);
        w1F[i] = f.q;
        return;
    }
    i -= 16 * NKT1 * 64;
    if (i < 16 * NKT2 * 64) {                       // w2 fragments
        int nt = i / (NKT2 * 64), rem = i % (NKT2 * 64);
        int kt = rem / 64, lane = rem % 64;
        int n  = nt * 16 + (lane & 15);
        int k0 = kt * 32 + (lane >> 4) * 8;
        const float* wc = w2 + n;
        ABFrag f;
        f.u[0] = pack2(wc[(k0 + 0) * FF], wc[(k0 + 1) * FF]);
        f.u[1] = pack2(wc[(k0 + 2) * FF], wc[(k0 + 3) * FF]);
        f.u[2] = pack2(wc[(k0 + 4) * FF], wc[(k0 + 5) * FF]);
        f.u[3] = pack2(wc[(k0 + 6) * FF], wc[(k0 + 7) * FF]);
        w2F[i] = f.q;
        return;
    }
    i -= 16 * NKT2 * 64;
    if (i < NB * N2) {                              // xq: pair records of 8 floats
        const float* q = xyz2 + (size_t)i * 3;
        float x = q[0], y = q[1], z = q[2];
        float s2 = __fadd_rn(__fadd_rn(__fmul_rn(x,x), __fmul_rn(y,y)), __fmul_rn(z,z));
        int p = i >> 1, e = i & 1;
        float* rec = xq + (size_t)p * 8;
        rec[0 + e] = -2.0f * x;
        rec[2 + e] = -2.0f * y;
        rec[4 + e] = -2.0f * z;
        rec[6 + e] = s2;
    }
}

// ---- fused: 3nn + interp + concat + mlp(2x); f32 in, f32 out, 16 waves ----
__global__ __launch_bounds__(NTHR, 8) void fp_fused_kernel(
    const float* __restrict__ xyz1, const float* __restrict__ p1,
    const float* __restrict__ p2,
    const u32x4* __restrict__ w1F,  const u32x4* __restrict__ w2F,
    const float4* __restrict__ xq,  float* __restrict__ out)
{
    __shared__ int   s_idx[TM][3];
    __shared__ float s_wt[TM][3];
    // A [TM][APAD] bf16 (51200 B) ; then pd/pi [NCH][TM][3] (24576 B). H overlays A.
    __shared__ __align__(16) char s_buf[ABYTES + NCH * TM * 3 * 8];

    const int tid = threadIdx.x;
    const int b   = blockIdx.x / TILES_PER_B;
    const int t0  = (blockIdx.x % TILES_PER_B) * TM;

    u16*   A  = (u16*)s_buf;
    float* pd = (float*)(s_buf + PDOFF);
    int*   pi = (int*)(s_buf + PIOFF);

    // ---------- phase 0: p1 -> A cols 256.. (no dependency on knn; overlaps scan) ----------
    {
        const int c4 = (tid & 31) * 4, r32 = tid >> 5;   // 0..31
        #pragma unroll
        for (int rv = 0; rv < 2; ++rv) {
            int rr = r32 + rv * 32;
            float4 v = *(const float4*)(p1 + ((size_t)b * N1 + t0 + rr) * C1 + c4);
            u32* w = (u32*)(A + rr * APAD + 256 + c4);
            w[0] = pack2(v.x, v.y);
            w[1] = pack2(v.z, v.w);
        }
    }

    // ---------- phase 1: 3-NN scan, packed 2-point math, scalar-load points ----------
    {
        const int r  = tid & 63;
        const int ch = __builtin_amdgcn_readfirstlane(tid >> 6);   // wave-uniform chunk
        const float4* cb = xq + ((size_t)b * (N2 / 2) + ch * (CHSZ / 2)) * 2;
        const float* q = xyz1 + ((size_t)b * N1 + t0 + r) * 3;
        float qx = q[0], qy = q[1], qz = q[2];
        float s1 = __fadd_rn(__fadd_rn(__fmul_rn(qx,qx), __fmul_rn(qy,qy)), __fmul_rn(qz,qz));
        float bd0 = 3e38f, bd1 = 3e38f, bd2 = 3e38f;
        int   bi0 = 0, bi1 = 0, bi2 = 0;
        const int j0 = ch * CHSZ;
        #pragma unroll 4
        for (int jj = 0; jj < CHSZ / 2; ++jj) {
            float4 f0 = cb[2 * jj];        // (nx0,nx1,ny0,ny1)
            float4 f1 = cb[2 * jj + 1];    // (nz0,nz1,s20,s21)
            f32x2 dpair;
            {
                #pragma clang fp contract(off)
                f32x2 qx2 = {qx, qx}, qy2 = {qy, qy}, qz2 = {qz, qz}, s1v = {s1, s1};
                f32x2 nx = {f0.x, f0.y}, ny = {f0.z, f0.w};
                f32x2 nz = {f1.x, f1.y}, ss = {f1.z, f1.w};
                f32x2 u  = qx2 * nx;
                f32x2 v  = qy2 * ny;
                f32x2 w  = u + v;
                f32x2 z2 = qz2 * nz;
                f32x2 t  = w + z2;         // t = -2*dot, exact (x2 scaling commutes with rounding)
                f32x2 s12 = s1v + ss;
                dpair = s12 + t;           // = (s1+s2) - 2*dot, bit-identical to np
            }
            #pragma unroll
            for (int e = 0; e < 2; ++e) {
                float d = dpair[e];
                int   j = j0 + 2 * jj + e;
                float nb0 = fminf(d, bd0);
                float nb1 = __builtin_amdgcn_fmed3f(d, bd0, bd1);
                float nb2 = __builtin_amdgcn_fmed3f(d, bd1, bd2);
                bool c0 = d < bd0, c1 = d < bd1, c2 = d < bd2;
                int t01 = c0 ? bi0 : j;
                bi0     = c0 ? j   : bi0;
                int t12 = c1 ? bi1 : j;
                bi1     = c1 ? t01 : bi1;
                bi2     = c2 ? t12 : bi2;
                bd0 = nb0; bd1 = nb1; bd2 = nb2;
            }
        }
        const int o = (ch * TM + r) * 3;
        pd[o+0] = bd0; pd[o+1] = bd1; pd[o+2] = bd2;
        pi[o+0] = bi0; pi[o+1] = bi1; pi[o+2] = bi2;
    }
    __syncthreads();

    // ---------- merge (branchless; ascending chunk order = ascending index) ----------
    if (tid < TM) {
        float d0 = 3e38f, d1 = 3e38f, d2 = 3e38f;
        int   i0 = 0, i1 = 0, i2 = 0;
        for (int c = 0; c < NCH; ++c) {
            const int o = (c * TM + tid) * 3;
            #pragma unroll
            for (int k = 0; k < 3; ++k) {
                float d = pd[o + k]; int ix = pi[o + k];
                float n0 = fminf(d, d0);
                float n1 = __builtin_amdgcn_fmed3f(d, d0, d1);
                float n2 = __builtin_amdgcn_fmed3f(d, d1, d2);
                bool c0 = d < d0, c1 = d < d1, c2 = d < d2;
                int t01 = c0 ? i0 : ix;
                i0      = c0 ? ix : i0;
                int t12 = c1 ? i1 : t01;
                i1      = c1 ? t01 : i1;
                i2      = c2 ? t12 : i2;
                d0 = n0; d1 = n1; d2 = n2;
            }
        }
        d0 = fmaxf(d0, 1e-10f); d1 = fmaxf(d1, 1e-10f); d2 = fmaxf(d2, 1e-10f);
        float v0 = 1.0f / d0, v1 = 1.0f / d1, v2 = 1.0f / d2;
        float s  = 1.0f / (v0 + v1 + v2);
        s_wt[tid][0] = v0 * s; s_wt[tid][1] = v1 * s; s_wt[tid][2] = v2 * s;
        s_idx[tid][0] = i0; s_idx[tid][1] = i1; s_idx[tid][2] = i2;
    }
    __syncthreads();

    // ---------- phase 2: interp -> A cols 0..255 (float4, wave-uniform row) ----------
    {
        const float* pb = p2 + (size_t)b * N2 * C2;
        const int col4 = (tid & 63) * 4;
        const int wvr  = tid >> 6;                       // 0..15
        #pragma unroll
        for (int m = 0; m < 4; ++m) {
            int rr = wvr + m * 16;
            float w0 = s_wt[rr][0], w1v = s_wt[rr][1], w2v = s_wt[rr][2];
            int   i0 = s_idx[rr][0], i1 = s_idx[rr][1], i2 = s_idx[rr][2];
            float4 a0 = *(const float4*)(pb + (size_t)i0 * C2 + col4);
            float4 a1 = *(const float4*)(pb + (size_t)i1 * C2 + col4);
            float4 a2 = *(const float4*)(pb + (size_t)i2 * C2 + col4);
            float e0 = w0 * a0.x + w1v * a1.x + w2v * a2.x;
            float e1 = w0 * a0.y + w1v * a1.y + w2v * a2.y;
            float e2 = w0 * a0.z + w1v * a1.z + w2v * a2.z;
            float e3 = w0 * a0.w + w1v * a1.w + w2v * a2.w;
            u32* w = (u32*)(A + rr * APAD + col4);
            w[0] = pack2(e0, e1);
            w[1] = pack2(e2, e3);
        }
    }
    __syncthreads();

    // ---------- phase 2.5: empirical C/D map probe (2 MFMAs) ----------
    const int lane = tid & 63;
    const int wv   = tid >> 6;          // 0..15, wave -> 16-col slice
    const int lr   = lane & 15;
    const int lg   = lane >> 4;         // 0..3
    const int wvb  = wv * 16;

    int id1[4], id2[4];
    {
        u16 rbf = f2b((float)lr);
        u16 c32 = f2b(1.0f / 32.0f);
        ABFrag pa, pc;
        u32 ra = (u32)rbf | ((u32)rbf << 16);
        u32 rc = (u32)c32 | ((u32)c32 << 16);
        pa.u[0] = pa.u[1] = pa.u[2] = pa.u[3] = ra;
        pc.u[0] = pc.u[1] = pc.u[2] = pc.u[3] = rc;
        floatx4 z = {0.f, 0.f, 0.f, 0.f};
        floatx4 D1 = __builtin_amdgcn_mfma_f32_16x16x32_bf16(pa.v, pc.v, z, 0, 0, 0); // row
        floatx4 D2 = __builtin_amdgcn_mfma_f32_16x16x32_bf16(pc.v, pa.v, z, 0, 0, 0); // col
        #pragma unroll
        for (int g = 0; g < 4; ++g) { id1[g] = (int)(D1[g] + 0.5f); id2[g] = (int)(D2[g] + 0.5f); }
    }

    // ---------- phase 3: GEMM1 (K=384), contiguous-k frags: 1 ds_read_b128 each ----------
    floatx4 acc[4];
    #pragma unroll
    for (int i = 0; i < 4; ++i) acc[i] = floatx4{0.f, 0.f, 0.f, 0.f};

    {
        const u32x4* wf = w1F + (size_t)(wv * NKT1) * 64 + lane;
        const int kb8 = lg * 8;
        for (int kk = 0; kk < NKT1; ++kk) {
            ABFrag bf; bf.q = wf[(size_t)kk * 64];
            ABFrag a[4];
            #pragma unroll
            for (int rt = 0; rt < 4; ++rt)
                a[rt].q = *(const u32x4*)(A + (rt * 16 + lr) * APAD + kk * 32 + kb8);
            #pragma unroll
            for (int rt = 0; rt < 4; ++rt)
                acc[rt] = __builtin_amdgcn_mfma_f32_16x16x32_bf16(a[rt].v, bf.v, acc[rt], 0, 0, 0);
        }
    }
    __syncthreads();   // all waves done reading A before H overwrites it

    // ---------- phase 4: h = relu(...) -> bf16 LDS [TM][HPAD], probe-mapped ----------
    u16* H = (u16*)s_buf;
    #pragma unroll
    for (int rt = 0; rt < 4; ++rt)
        #pragma unroll
        for (int g = 0; g < 4; ++g) {
            int row = rt * 16 + id1[g];
            int col = wvb + id2[g];
            H[row * HPAD + col] = f2b(fmaxf(acc[rt][g], 0.0f));
        }
    __syncthreads();

    // ---------- phase 5: GEMM2 (K=256) ----------
    floatx4 acc2[4];
    #pragma unroll
    for (int i = 0; i < 4; ++i) acc2[i] = floatx4{0.f, 0.f, 0.f, 0.f};

    {
        const u32x4* wf = w2F + (size_t)(wv * NKT2) * 64 + lane;
        const int kb8 = lg * 8;
        for (int kk = 0; kk < NKT2; ++kk) {
            ABFrag bf; bf.q = wf[(size_t)kk * 64];
            ABFrag a[4];
            #pragma unroll
            for (int rt = 0; rt < 4; ++rt)
                a[rt].q = *(const u32x4*)(H + (rt * 16 + lr) * HPAD + kk * 32 + kb8);
            #pragma unroll
            for (int rt = 0; rt < 4; ++rt)
                acc2[rt] = __builtin_amdgcn_mfma_f32_16x16x32_bf16(a[rt].v, bf.v, acc2[rt], 0, 0, 0);
        }
    }

    // ---------- phase 6: relu -> f32 -> global, probe-mapped ----------
    float* ob = out + ((size_t)b * N1 + t0) * FF;
    #pragma unroll
    for (int rt = 0; rt < 4; ++rt)
        #pragma unroll
        for (int g = 0; g < 4; ++g) {
            int row = rt * 16 + id1[g];
            int col = wvb + id2[g];
            ob[(size_t)row * FF + col] = fmaxf(acc2[rt][g], 0.0f);
        }
}

extern "C" void kernel_launch(void* const* d_in, const int* in_sizes, int n_in,
                              void* d_out, int out_size, void* d_ws, size_t ws_size,
                              hipStream_t stream)
{
    (void)in_sizes; (void)n_in; (void)out_size; (void)ws_size;
    const float* xyz1 = (const float*)d_in[0];
    const float* xyz2 = (const float*)d_in[1];
    const float* p1   = (const float*)d_in[2];
    const float* p2   = (const float*)d_in[3];
    const float* w1   = (const float*)d_in[4];
    const float* w2   = (const float*)d_in[5];
    float* out = (float*)d_out;

    u32x4* w1F = (u32x4*)d_ws;                      // 196608 B
    u32x4* w2F = w1F + 16 * NKT1 * 64;              // 131072 B
    float* xqw = (float*)(w2F + 16 * NKT2 * 64);    // 4096 pair-records * 32 B = 131072 B

    int prep_items = 16 * NKT1 * 64 + 16 * NKT2 * 64 + NB * N2;
    prep_kernel<<<(prep_items + 255) / 256, 256, 0, stream>>>(w1, w2, xyz2, w1F, w2F, xqw);
    fp_fused_kernel<<<NB * TILES_PER_B, NTHR, 0, stream>>>(
        xyz1, p1, p2, w1F, w2F, (const float4*)xqw, out);
}